// Round 1
// 146.496 us; speedup vs baseline: 1.0251x; 1.0251x over previous
//
#include <hip/hip_runtime.h>
#include <hip/hip_bf16.h>

// Fused single-kernel version, v2: scalar-pipe weights.
// B=262144 rows, out [B,100] fp32 = 104.9 MB -> ~16.5 us write floor at the
// fill-measured 6.5 TB/s.
// v1 kept all MLP weights in LDS; every mlp_pair call broadcast ~284 KB of
// ds_read_b128 per wave (270 b128 reads) to deliver 4.3 KB of wave-uniform
// weights -> ~11 us/CU of LDS-bound time (vs ~1.7 us of v_pk_fma_f32).
// v2 reads weights directly from global with uniform compile-time indices so
// they lower to s_load_* (scalar cache) and feed v_pk_fma as SGPR operands.
// Arithmetic order is bitwise-identical to v1 (same sa/sb FMA chains), so
// absmax must reproduce exactly (0.015625).
// Structure per block (256 blocks x 256 threads, 1024 rows/block):
//   prep (Cost/Pmax->LDS, sum Pd, cumprev)
//   chain0: packed MLP for rows [0,512)   -> td in LDS
//   barrier
//   store batch0 (posted writes drain in background) ; chain1: rows [512,1024)
//   barrier
//   store batch1
// Bound: t_first_store + 16.4 us total drain. v2 attacks t_first_store.

typedef float f2 __attribute__((ext_vector_type(2)));

#define NBLOCKS 256
#define ROWS_PER_BLOCK 1024

// smem layout (floats)
#define OFF_CP 0      // cumprev[j]                                    (100)
#define OFF_PM 100    // Pmax staged                                   (100)
#define OFF_CS 200    // Cost staged                                   (100)
#define OFF_SPD 300   // sum(Pd)                                       (1)
#define OFF_Y 304     // td buffer, 1024 rows (16B-aligned: 304*4=1216)
#define SMEM_FLOATS (OFF_Y + ROWS_PER_BLOCK)

__device__ __forceinline__ f2 splat(float v) { return (f2){v, v}; }

// Packed MLP for two rows (xa -> .x lane, xb -> .y lane). Returns total_d pair.
// All weight accesses are wave-uniform indices into global memory -> scalar
// loads on the SMEM pipe; zero LDS traffic in here.
__device__ __forceinline__ f2 mlp_pair(const float4 xa, const float4 xb,
                                       const float* __restrict__ W1,
                                       const float* __restrict__ b1,
                                       const float* __restrict__ W2,
                                       const float* __restrict__ b2,
                                       const float* __restrict__ W3,
                                       float wc, float b3v, float spd) {
  const f2 X0 = {xa.x, xb.x}, X1 = {xa.y, xb.y};
  const f2 X2 = {xa.z, xb.z}, X3 = {xa.w, xb.w};
  const f2 zero = {0.0f, 0.0f};

  f2 h1[30];
#pragma unroll
  for (int k = 0; k < 30; ++k) {
    f2 p = splat(b1[k]);
    p = __builtin_elementwise_fma(X0, splat(W1[0 * 30 + k]), p);
    p = __builtin_elementwise_fma(X1, splat(W1[1 * 30 + k]), p);
    p = __builtin_elementwise_fma(X2, splat(W1[2 * 30 + k]), p);
    p = __builtin_elementwise_fma(X3, splat(W1[3 * 30 + k]), p);
    h1[k] = __builtin_elementwise_max(p, zero);
  }

  f2 y = zero;
#pragma unroll 5
  for (int k = 0; k < 30; ++k) {
    // two partial accumulators -> two independent FMA chains (latency hiding
    // matters: only 1 wave/SIMD at this grid). Same association as v1.
    f2 sa = zero, sb = zero;
#pragma unroll
    for (int c = 0; c < 7; ++c) {
      sa = __builtin_elementwise_fma(h1[4 * c],     splat(W2[(4 * c + 0) * 30 + k]), sa);
      sb = __builtin_elementwise_fma(h1[4 * c + 1], splat(W2[(4 * c + 1) * 30 + k]), sb);
      sa = __builtin_elementwise_fma(h1[4 * c + 2], splat(W2[(4 * c + 2) * 30 + k]), sa);
      sb = __builtin_elementwise_fma(h1[4 * c + 3], splat(W2[(4 * c + 3) * 30 + k]), sb);
    }
    sa = __builtin_elementwise_fma(h1[28], splat(W2[28 * 30 + k]), sa);
    sb = __builtin_elementwise_fma(h1[29], splat(W2[29 * 30 + k]), sb);
    f2 s2 = sa + sb + splat(b2[k]);
    s2 = __builtin_elementwise_max(s2, zero);
    y = __builtin_elementwise_fma(s2, splat(W3[k]), y);
  }

  f2 td;
  td.x = spd - wc * (y.x + b3v);
  td.y = spd - wc * (y.y + b3v);
  return td;
}

__device__ __forceinline__ void store_batch(float* __restrict__ op0,
                                            const float* __restrict__ ytd,
                                            const float4 cpr, const float4 pmx,
                                            int t) {
  if (t < 200) {
    const int g = t % 25;
    int r = t / 25;
    float* __restrict__ op = op0 + r * 100 + g * 4;
#pragma unroll 4
    for (int it = 0; it < 64; ++it) {
      const float td = ytd[r];
      float4 v;
      v.x = fminf(fmaxf(td - cpr.x, 0.0f), pmx.x);
      v.y = fminf(fmaxf(td - cpr.y, 0.0f), pmx.y);
      v.z = fminf(fmaxf(td - cpr.z, 0.0f), pmx.z);
      v.w = fminf(fmaxf(td - cpr.w, 0.0f), pmx.w);
      *(float4*)op = v;
      r += 8;
      op += 800;
    }
  }
}

__global__ __launch_bounds__(256, 1) void e2e_mlp_fused_kernel(
    const float* __restrict__ x,    const float* __restrict__ Cost,
    const float* __restrict__ Pmax, const float* __restrict__ Pd,
    const float* __restrict__ wcapp,const float* __restrict__ W1,
    const float* __restrict__ b1,   const float* __restrict__ W2,
    const float* __restrict__ b2,   const float* __restrict__ W3,
    const float* __restrict__ b3p,  float* __restrict__ out) {
  __shared__ float s[SMEM_FLOATS];
  const int t = threadIdx.x;
  const long rbase = (long)blockIdx.x * ROWS_PER_BLOCK;

  // ---- prep: stage Cost/Pmax, sum(Pd) ----
  if (t < 100) {
    s[OFF_PM + t] = Pmax[t];
    s[OFF_CS + t] = Cost[t];
  }
  // sum(Pd): lanes 0..24 hold float4 partials, full-wave shfl reduce.
  {
    float p = 0.0f;
    if (t < 25) {
      const float4 q = ((const float4*)Pd)[t];
      p = q.x + q.y + q.z + q.w;
    }
    for (int off = 32; off; off >>= 1) p += __shfl_down(p, off, 64);
    if (t == 0) s[OFF_SPD] = p;
  }
  __syncthreads();  // B0

  // cumprev via O(N^2) rank-sum (stable tie-break == jnp stable argsort)
  if (t < 100) {
    const float c = s[OFF_CS + t];
    float acc = 0.0f;
    for (int i = 0; i < 100; ++i) {
      const float ci = s[OFF_CS + i];
      const bool cheaper = (ci < c) || (ci == c && i < t);
      acc += cheaper ? s[OFF_PM + i] : 0.0f;
    }
    s[OFF_CP + t] = acc;
  }

  const float wc  = wcapp[0];
  const float b3v = b3p[0];
  const float spd = s[OFF_SPD];
  const float4* __restrict__ x4 = (const float4*)x;

  // ---- chain 0: rows [0,512) of this block ----
  {
    const float4 xa = x4[rbase + t];
    const float4 xb = x4[rbase + 256 + t];
    const f2 td = mlp_pair(xa, xb, W1, b1, W2, b2, W3, wc, b3v, spd);
    s[OFF_Y + t]       = td.x;
    s[OFF_Y + 256 + t] = td.y;
  }
  __syncthreads();  // B1 (covers cumprev + ybuf[0..511])

  float4 cpr = {0, 0, 0, 0}, pmx = {0, 0, 0, 0};
  if (t < 200) {
    const int g = t % 25;
    cpr = *(const float4*)&s[OFF_CP + g * 4];
    pmx = *(const float4*)&s[OFF_PM + g * 4];
  }

  // batch-0 stores issue here; chain-1 compute runs while they drain.
  store_batch(out + rbase * 100, &s[OFF_Y], cpr, pmx, t);

  // ---- chain 1: rows [512,1024) ----
  {
    const float4 xa = x4[rbase + 512 + t];
    const float4 xb = x4[rbase + 768 + t];
    const f2 td = mlp_pair(xa, xb, W1, b1, W2, b2, W3, wc, b3v, spd);
    s[OFF_Y + 512 + t] = td.x;
    s[OFF_Y + 768 + t] = td.y;
  }
  __syncthreads();  // B2

  store_batch(out + (rbase + 512) * 100, &s[OFF_Y + 512], cpr, pmx, t);
}

extern "C" void kernel_launch(void* const* d_in, const int* in_sizes, int n_in,
                              void* d_out, int out_size, void* d_ws, size_t ws_size,
                              hipStream_t stream) {
  const float* x    = (const float*)d_in[0];
  const float* Cost = (const float*)d_in[1];
  const float* Pmax = (const float*)d_in[2];
  const float* Pd   = (const float*)d_in[3];
  const float* wcap = (const float*)d_in[4];
  const float* W1   = (const float*)d_in[5];
  const float* b1   = (const float*)d_in[6];
  const float* W2   = (const float*)d_in[7];
  const float* b2   = (const float*)d_in[8];
  const float* W3   = (const float*)d_in[9];
  const float* b3   = (const float*)d_in[10];
  float* out = (float*)d_out;

  e2e_mlp_fused_kernel<<<NBLOCKS, 256, 0, stream>>>(
      x, Cost, Pmax, Pd, wcap, W1, b1, W2, b2, W3, b3, out);
}